// Round 10
// baseline (58.355 us; speedup 1.0000x reference)
//
#include <hip/hip_runtime.h>

// 2-level separable db4 DWT, pywt 'symmetric', fused, rolling-row version v9.
// x: (8, 512, 512, 16) f32 -> out: concat(aa, ad, da, dd), each (8, 259, 259, 16) f32.
//
// v9: W=128 column band (JB=61) -> 3.9 KB contiguous write bursts per
// subband per iteration (2x r8) and halved horizontal halo. Each thread
// owns 2 column-slots with two statically-indexed 8-row register FIFOs.
// Store path: builtin nontemporal (coherent) — the sc0/sc1 IC-bypass
// variant of r9 is UNSOUND (memory-side IC holds harness memset lines).

constexpr int N  = 512;
constexpr int ON = 259;          // (N + 8 - 1) / 2
constexpr int CH = 16;
constexpr int NB = 8;
constexpr int JB = 61;           // output cols per band
constexpr int BANDS = 5;         // 5*61 = 305 >= 259
constexpr int RS = 16;           // output rows per segment (constant trip)
constexpr int SEGS = 17;         // 17*16 = 272 >= 259
constexpr int W  = 2 * JB + 6;   // 128 input cols per band
constexpr int LSTR = 20;         // padded word stride per column

typedef float vfloat4 __attribute__((ext_vector_type(4)));

__device__ __forceinline__ int refl(int r) {
  r = (r < 0) ? (-r - 1) : r;
  return (r >= N) ? (2 * N - 1 - r) : r;
}

__device__ __forceinline__ int lds_idx(int c, int w) {
  return c * LSTR + ((w + ((c >> 2) << 2)) & 15);
}

// Barrier with LDS-write visibility but WITHOUT draining vmcnt.
__device__ __forceinline__ void block_sync_lds() {
  asm volatile("s_waitcnt lgkmcnt(0)" ::: "memory");
  __builtin_amdgcn_s_barrier();
  __builtin_amdgcn_sched_barrier(0);
}

__device__ __forceinline__ void nt_store4(float* p, float4 v) {
  vfloat4 nv = {v.x, v.y, v.z, v.w};
  __builtin_nontemporal_store(nv, reinterpret_cast<vfloat4*>(p));
}

__global__ __launch_bounds__(256) void dwt2_ring(
    const float* __restrict__ x, const float* __restrict__ dec_lo,
    float* __restrict__ out)
{
  const int band = blockIdx.x, seg = blockIdx.y, b = blockIdx.z;
  const int j0 = band * JB;
  const int i0 = seg * RS;
  const int t  = threadIdx.x;
  const int tc  = t >> 2;            // base column slot (0..63)
  const int tch = (t & 3) << 2;      // channel word (0,4,8,12)

  __shared__ float a_buf[2][W * LSTR];  // 2 x 10 KB
  __shared__ float d_buf[2][W * LSTR];  // 2 x 10 KB

  float lo[8], hi[8];
#pragma unroll
  for (int m = 0; m < 8; ++m) lo[m] = dec_lo[7 - m];
#pragma unroll
  for (int m = 0; m < 8; ++m) hi[m] = (m & 1) ? -dec_lo[m] : dec_lo[m];

  // Two column-slots per thread: c0 = tc, c1 = tc + 64.
  const int c0 = tc, c1 = tc + 64;
  const int gc0 = refl(2 * j0 - 6 + c0);
  const int gc1 = refl(2 * j0 - 6 + c1);
  const float* xb = x + (size_t)b * N * N * CH;
  const float* colp0 = xb + (size_t)gc0 * CH + tch;
  const float* colp1 = xb + (size_t)gc1 * CH + tch;

  auto ldrow0 = [&](int r) -> float4 {
    return *reinterpret_cast<const float4*>(colp0 + (size_t)refl(r) * (N * CH));
  };
  auto ldrow1 = [&](int r) -> float4 {
    return *reinterpret_cast<const float4*>(colp1 + (size_t)refl(r) * (N * CH));
  };

  // Two 8-row register FIFOs (statically indexed under full unroll).
  float4 f0[8], f1[8];
#pragma unroll
  for (int m = 0; m < 8; ++m) f0[m] = ldrow0(2 * i0 - 6 + m);
#pragma unroll
  for (int m = 0; m < 8; ++m) f1[m] = ldrow1(2 * i0 - 6 + m);

  // Stage-B mapping: 488 work slots; thread t handles q = t and q = t+256.
  // q < 244 -> aa/ad from a_buf; 244 <= q < 488 -> da/dd from d_buf.
  const size_t OUTSZ = (size_t)NB * ON * ON * CH;

  const int q0 = t;                 // always valid (q0 < 244 or in-range)
  const int sb0 = (q0 >= 244);
  const int p0  = q0 - 244 * sb0;
  const int jr0 = p0 >> 2, bw0 = (p0 & 3) << 2;
  const int jA  = j0 + jr0;
  const bool v0ok = (jA < ON);
  float* o_lo0 = out + (size_t)(2 * sb0) * OUTSZ;
  float* o_hi0 = o_lo0 + OUTSZ;

  const int q1 = t + 256;
  const bool q1valid = (q1 < 488);
  const int sb1 = 1;                // q1 >= 256 > 244 always
  const int p1  = q1 - 244;
  const int jr1 = p1 >> 2, bw1 = (p1 & 3) << 2;
  const int jB  = j0 + jr1;
  const bool v1ok = q1valid && (jB < ON);
  float* o_lo1 = out + (size_t)(2 * sb1) * OUTSZ;
  float* o_hi1 = o_lo1 + OUTSZ;

  const int widx0 = lds_idx(c0, tch);
  const int widx1 = lds_idx(c1, tch);

#pragma unroll
  for (int it = 0; it < RS; ++it) {
    const int i = i0 + it;
    const int cur = it & 1;

    // ---- Stage A: vertical DWT from both register FIFOs
    float4 av0 = {0,0,0,0}, dv0 = {0,0,0,0}, av1 = {0,0,0,0}, dv1 = {0,0,0,0};
#pragma unroll
    for (int m = 0; m < 8; ++m) {
      av0.x += lo[m] * f0[m].x; av0.y += lo[m] * f0[m].y;
      av0.z += lo[m] * f0[m].z; av0.w += lo[m] * f0[m].w;
      dv0.x += hi[m] * f0[m].x; dv0.y += hi[m] * f0[m].y;
      dv0.z += hi[m] * f0[m].z; dv0.w += hi[m] * f0[m].w;
      av1.x += lo[m] * f1[m].x; av1.y += lo[m] * f1[m].y;
      av1.z += lo[m] * f1[m].z; av1.w += lo[m] * f1[m].w;
      dv1.x += hi[m] * f1[m].x; dv1.y += hi[m] * f1[m].y;
      dv1.z += hi[m] * f1[m].z; dv1.w += hi[m] * f1[m].w;
    }

    // Shift FIFOs by 2; prefetch rows 2i+2, 2i+3 for next iteration.
    // Elided on the last iteration (compile-time under full unroll).
#pragma unroll
    for (int k = 0; k < 6; ++k) { f0[k] = f0[k + 2]; f1[k] = f1[k + 2]; }
    if (it + 1 < RS) {
      f0[6] = ldrow0(2 * i + 2);
      f0[7] = ldrow0(2 * i + 3);
      f1[6] = ldrow1(2 * i + 2);
      f1[7] = ldrow1(2 * i + 3);
    }

    *reinterpret_cast<float4*>(&a_buf[cur][widx0]) = av0;
    *reinterpret_cast<float4*>(&d_buf[cur][widx0]) = dv0;
    *reinterpret_cast<float4*>(&a_buf[cur][widx1]) = av1;
    *reinterpret_cast<float4*>(&d_buf[cur][widx1]) = dv1;

    block_sync_lds();

    // ---- Stage B: horizontal DWT from LDS, 2 work slots per thread
    if (i < ON) {
      if (v0ok) {
        const float* src = sb0 ? d_buf[cur] : a_buf[cur];
        float4 aL = {0,0,0,0}, aH = {0,0,0,0};
#pragma unroll
        for (int m = 0; m < 8; ++m) {
          const float4 s = *reinterpret_cast<const float4*>(
              &src[lds_idx(2 * jr0 + m, bw0)]);
          aL.x += lo[m] * s.x; aL.y += lo[m] * s.y;
          aL.z += lo[m] * s.z; aL.w += lo[m] * s.w;
          aH.x += hi[m] * s.x; aH.y += hi[m] * s.y;
          aH.z += hi[m] * s.z; aH.w += hi[m] * s.w;
        }
        const size_t o = (((size_t)b * ON + i) * ON + jA) * CH + bw0;
        nt_store4(o_lo0 + o, aL);
        nt_store4(o_hi0 + o, aH);
      }
      if (v1ok) {
        const float* src = d_buf[cur];
        float4 aL = {0,0,0,0}, aH = {0,0,0,0};
#pragma unroll
        for (int m = 0; m < 8; ++m) {
          const float4 s = *reinterpret_cast<const float4*>(
              &src[lds_idx(2 * jr1 + m, bw1)]);
          aL.x += lo[m] * s.x; aL.y += lo[m] * s.y;
          aL.z += lo[m] * s.z; aL.w += lo[m] * s.w;
          aH.x += hi[m] * s.x; aH.y += hi[m] * s.y;
          aH.z += hi[m] * s.z; aH.w += hi[m] * s.w;
        }
        const size_t o = (((size_t)b * ON + i) * ON + jB) * CH + bw1;
        nt_store4(o_lo1 + o, aL);
        nt_store4(o_hi1 + o, aH);
      }
    }
  }
}

extern "C" void kernel_launch(void* const* d_in, const int* in_sizes, int n_in,
                              void* d_out, int out_size, void* d_ws, size_t ws_size,
                              hipStream_t stream) {
  const float* x      = (const float*)d_in[0];
  const float* dec_lo = (const float*)d_in[1];
  float* out          = (float*)d_out;
  dim3 grid(BANDS, SEGS, NB);
  dwt2_ring<<<grid, 256, 0, stream>>>(x, dec_lo, out);
}

// Round 11
// 55.072 us; speedup vs baseline: 1.0596x; 1.0596x over previous
//
#include <hip/hip_runtime.h>

// 2-level separable db4 DWT, pywt 'symmetric', fused, rolling-row version v7.
// x: (8, 512, 512, 16) f32 -> out: concat(aa, ad, da, dd), each (8, 259, 259, 16) f32.
//
// FINAL (revert to best-measured r8 config): 1224 blocks (9x17x8), RS=16,
// 8-row register FIFO, double-buffered 20 KB LDS stage, lgkmcnt-only
// barrier, nontemporal (coherent) stores. Measured 57.16 us; TCC-visible
// HBM = 89 MB fetch (sub-compulsory) + 135 MB write (compulsory).

constexpr int N  = 512;
constexpr int ON = 259;          // (N + 8 - 1) / 2
constexpr int CH = 16;
constexpr int NB = 8;
constexpr int JB = 29;           // output cols per band
constexpr int BANDS = 9;         // 9*29 = 261 >= 259
constexpr int RS = 16;           // output rows per segment (constant trip)
constexpr int SEGS = 17;         // 17*16 = 272 >= 259
constexpr int W  = 2 * JB + 6;   // 64 input cols per band
constexpr int LSTR = 20;         // padded word stride per column

typedef float vfloat4 __attribute__((ext_vector_type(4)));

__device__ __forceinline__ int refl(int r) {
  r = (r < 0) ? (-r - 1) : r;
  return (r >= N) ? (2 * N - 1 - r) : r;
}

__device__ __forceinline__ int lds_idx(int c, int w) {
  return c * LSTR + ((w + ((c >> 2) << 2)) & 15);
}

// Barrier with LDS-write visibility but WITHOUT draining vmcnt.
__device__ __forceinline__ void block_sync_lds() {
  asm volatile("s_waitcnt lgkmcnt(0)" ::: "memory");
  __builtin_amdgcn_s_barrier();
  __builtin_amdgcn_sched_barrier(0);
}

__device__ __forceinline__ void nt_store4(float* p, float4 v) {
  vfloat4 nv = {v.x, v.y, v.z, v.w};
  __builtin_nontemporal_store(nv, reinterpret_cast<vfloat4*>(p));
}

__global__ __launch_bounds__(256) void dwt2_ring(
    const float* __restrict__ x, const float* __restrict__ dec_lo,
    float* __restrict__ out)
{
  const int band = blockIdx.x, seg = blockIdx.y, b = blockIdx.z;
  const int j0 = band * JB;
  const int i0 = seg * RS;
  const int t  = threadIdx.x;
  const int tc = t >> 2;             // column within band (0..63)
  const int tch = (t & 3) << 2;      // channel word (0,4,8,12)

  __shared__ float a_buf[2][W * LSTR];  // 2 x 5 KB
  __shared__ float d_buf[2][W * LSTR];  // 2 x 5 KB

  float lo[8], hi[8];
#pragma unroll
  for (int m = 0; m < 8; ++m) lo[m] = dec_lo[7 - m];
#pragma unroll
  for (int m = 0; m < 8; ++m) hi[m] = (m & 1) ? -dec_lo[m] : dec_lo[m];

  const int gc = refl(2 * j0 - 6 + tc);
  const float* xb   = x + (size_t)b * N * N * CH;
  const float* colp = xb + (size_t)gc * CH + tch;

  auto ldrow = [&](int r) -> float4 {
    return *reinterpret_cast<const float4*>(colp + (size_t)refl(r) * (N * CH));
  };

  // 8-row register FIFO: f[k] holds input row 2i-6+k.
  float4 f[8];
#pragma unroll
  for (int m = 0; m < 8; ++m) f[m] = ldrow(2 * i0 - 6 + m);

  // Stage-B mapping: threads 0..115 -> aa/ad from a_buf; 116..231 -> da/dd
  // from d_buf; 232..255 idle in stage B.
  const int  sb  = (t >= 116);
  const int  p   = sb ? (t - 116) : t;
  const int  jr  = p >> 2;
  const int  bch = (p & 3) << 2;
  const int  j   = j0 + jr;
  const bool wr  = (t < 232) && (j < ON);
  const size_t OUTSZ = (size_t)NB * ON * ON * CH;
  float* o_lo = out + (size_t)(2 * sb) * OUTSZ;   // aa or da
  float* o_hi = o_lo + OUTSZ;                     // ad or dd

  const int widx = lds_idx(tc, tch);

#pragma unroll
  for (int it = 0; it < RS; ++it) {
    const int i = i0 + it;
    const int cur = it & 1;

    // ---- Stage A: vertical DWT from the register FIFO (rows 2i-6..2i+1)
    float4 av = {0.f, 0.f, 0.f, 0.f}, dv = {0.f, 0.f, 0.f, 0.f};
#pragma unroll
    for (int m = 0; m < 8; ++m) {
      av.x += lo[m] * f[m].x; av.y += lo[m] * f[m].y;
      av.z += lo[m] * f[m].z; av.w += lo[m] * f[m].w;
      dv.x += hi[m] * f[m].x; dv.y += hi[m] * f[m].y;
      dv.z += hi[m] * f[m].z; dv.w += hi[m] * f[m].w;
    }

    // Shift FIFO by 2; issue loads for rows 2i+2, 2i+3 (used next iter).
    // Elided on the last iteration (compile-time under full unroll).
#pragma unroll
    for (int k = 0; k < 6; ++k) f[k] = f[k + 2];
    if (it + 1 < RS) {
      f[6] = ldrow(2 * i + 2);
      f[7] = ldrow(2 * i + 3);
    }

    *reinterpret_cast<float4*>(&a_buf[cur][widx]) = av;
    *reinterpret_cast<float4*>(&d_buf[cur][widx]) = dv;

    block_sync_lds();

    // ---- Stage B: horizontal DWT from LDS -> 2 subbands per thread
    if (wr && i < ON) {
      const float* src = sb ? d_buf[cur] : a_buf[cur];
      float4 aL = {0.f, 0.f, 0.f, 0.f}, aH = {0.f, 0.f, 0.f, 0.f};
#pragma unroll
      for (int m = 0; m < 8; ++m) {
        const float4 s = *reinterpret_cast<const float4*>(
            &src[lds_idx(2 * jr + m, bch)]);
        aL.x += lo[m] * s.x; aL.y += lo[m] * s.y;
        aL.z += lo[m] * s.z; aL.w += lo[m] * s.w;
        aH.x += hi[m] * s.x; aH.y += hi[m] * s.y;
        aH.z += hi[m] * s.z; aH.w += hi[m] * s.w;
      }
      const size_t o = (((size_t)b * ON + i) * ON + j) * CH + bch;
      nt_store4(o_lo + o, aL);
      nt_store4(o_hi + o, aH);
    }
  }
}

extern "C" void kernel_launch(void* const* d_in, const int* in_sizes, int n_in,
                              void* d_out, int out_size, void* d_ws, size_t ws_size,
                              hipStream_t stream) {
  const float* x      = (const float*)d_in[0];
  const float* dec_lo = (const float*)d_in[1];
  float* out          = (float*)d_out;
  dim3 grid(BANDS, SEGS, NB);
  dwt2_ring<<<grid, 256, 0, stream>>>(x, dec_lo, out);
}